// Round 11
// baseline (50.399 us; speedup 1.0000x reference)
//
#include <hip/hip_runtime.h>
#include <math.h>

#define NPIX (512*1024)   // H*W = 524288
#define NB   8
#define KBINS 16
#define CBINS 4
#define NACC 68           // 64 p_cl + 4 p_l  (p_c derived as row-sums of p_cl)
#define BLOCKS 1024
#define TPB 256
#define PXB 512           // pixels per block
#define HROWS 18          // rows 2..17 = bins 0..15; rows 0,1 = trash (out-of-range window mass)
#define HCOLS 512         // one column per pixel; col = px (bank = t%32, conflict-free)
#define SBUF (7*512)      // 3584 floats = 14KB per stage buffer

__device__ __forceinline__ float fexp2(float x){ return __builtin_amdgcn_exp2f(x); }
__device__ __forceinline__ float frcp (float x){ return __builtin_amdgcn_rcpf(x); }

// Windowed camera histogram update (math proven exact since R7, absmax 0.0):
// only edges jr-1, jr, jr+1 are non-saturated in fp32 (scale 200, bin 1/16).
// Window bins jr-2..jr+1 live at rows jr..jr+3; rows 18,19 fold onto trash
// rows 0,1 (never read back; collisions are same-thread serial adds, benign).
__device__ __forceinline__ void camWin(float gsum, float* __restrict__ col)
{
    constexpr float L2E  = 1.4426950408889634f;
    constexpr float ESTP = 12.5f * L2E;
    float u  = gsum * (16.0f / 3.0f);
    float jr = rintf(u);
    float d  = u - jr;                          // [-0.5, 0.5]
    int   ji = (int)jr;                         // 0..16
    float em = fexp2(fmaf(d, -ESTP, -ESTP));    // 2^(-ESTP*(d+1))
    float ep = fexp2(fmaf(d,  ESTP, -ESTP));    // 2^( ESTP*(d-1))
    float s0 = frcp(1.0f + fexp2(-ESTP * d));
    int r2 = (ji <= 15) ? ji + 2 : ji - 16;     // 18 -> 0 (trash)
    int r3 = (ji <= 14) ? ji + 3 : ji - 15;     // 18,19 -> 0,1 (trash)
    col[ji * HCOLS]       += em;
    col[(ji + 1) * HCOLS] += 1.0f - em - s0;
    col[r2 * HCOLS]       += s0 - ep;
    col[r3 * HCOLS]       += ep;
}

// Label path (proven, absmax 0.0): soft-argmax (beta=500) + single live edge.
__device__ __forceinline__ void labelAccum(float x0, float x1, float x2, float x3,
                                           float (&pl)[CBINS])
{
    constexpr float L2E = 1.4426950408889634f;
    constexpr float BSC = 500.0f * L2E;
    constexpr float LSC = 1000.0f * L2E;
    float m  = fmaxf(fmaxf(x0, x1), fmaxf(x2, x3));
    float mk = m * BSC;
    float e0 = fexp2(fmaf(x0, BSC, -mk));
    float e1 = fexp2(fmaf(x1, BSC, -mk));
    float e2 = fexp2(fmaf(x2, BSC, -mk));
    float e3 = fexp2(fmaf(x3, BSC, -mk));
    float am = fmaf(3.0f, e3, fmaf(2.0f, e2, e1)) * frcp(e0 + e1 + e2 + e3 + 1e-12f);

    float fj = rintf(am + 0.5f);                            // nearest edge (0..4)
    float v  = frcp(1.0f + fexp2((fj - 0.5f - am) * LSC));  // sigma at that edge
    #pragma unroll
    for (int c = 0; c < CBINS; c++) {
        float add = (fj == (float)(c + 1)) ? (1.0f - v)
                  : (fj == (float)c)       ? v : 0.0f;
        pl[c] += add;
    }
}

// global_load_lds staging + counted vmcnt + raw s_barrier (T3/T4 pattern):
// the DMA's in-flight state lives in LDS/vmcnt, so the compiler cannot sink
// the prefetch (which it did to every register pipeline, R5/R9/R10).
// 3 buffers, prefetch depth 2: 12 x 1KB wave-loads in flight per wave.
__launch_bounds__(TPB, 2)
__global__ void nid_partial(const float* __restrict__ cam,
                            const float* __restrict__ lab,
                            float* __restrict__ ws)
{
    __shared__ float stage[3][SBUF];        // 42KB
    __shared__ float hist[HROWS * HCOLS];   // 36KB; reused for reduction staging

    const int t  = threadIdx.x;
    const int nb = blockIdx.x * PXB;        // this block's first pixel

    // zero own hist columns (col t and col 256+t) -> private, no barrier
    #pragma unroll
    for (int r = 0; r < HROWS; r++) {
        hist[r * HCOLS + t]       = 0.0f;
        hist[r * HCOLS + 256 + t] = 0.0f;
    }

    // Stage batch b's 7 planes (14KB) into stage[buf]. 4 x 16B chunks per
    // thread; chunk 768+(t&127) is duplicate-staged by two waves (same src,
    // same dst, benign) so every wave issues exactly 4 loads -> uniform vmcnt.
    auto STAGE = [&](int b, int buf) {
        #pragma unroll
        for (int i = 0; i < 4; i++) {
            int c  = (i < 3) ? (t + 256 * i) : (768 + (t & 127));  // 0..895
            int pl = c >> 7;                                        // plane 0..6
            int w  = c & 127;                                       // 16B chunk in plane
            const float* src = (pl < 3)
                ? cam + (size_t)(b * 3 + pl) * NPIX + nb + w * 4
                : lab + (size_t)(b * 4 + (pl - 3)) * NPIX + nb + w * 4;
            __builtin_amdgcn_global_load_lds(
                (const __attribute__((address_space(1))) void*)src,
                (__attribute__((address_space(3))) void*)&stage[buf][c * 4],
                16, 0, 0);
        }
    };

    float pl0[CBINS] = {0.f, 0.f, 0.f, 0.f};
    float pl1[CBINS] = {0.f, 0.f, 0.f, 0.f};

    STAGE(0, 0);
    STAGE(1, 1);

    #pragma unroll
    for (int b = 0; b < NB; b++) {
        if (b + 2 < NB) {
            STAGE(b + 2, (b + 2) % 3);
            asm volatile("s_waitcnt vmcnt(8)" ::: "memory");   // batch b done; b+1,b+2 in flight
        } else if (b + 1 < NB) {
            asm volatile("s_waitcnt vmcnt(4)" ::: "memory");
        } else {
            asm volatile("s_waitcnt vmcnt(0)" ::: "memory");
        }
        __builtin_amdgcn_s_barrier();       // raw: no vmcnt(0) drain
        __builtin_amdgcn_sched_barrier(0);

        const float* sb = stage[b % 3];
        // px0 = t, px1 = 256+t: all ds_reads at bank t%32, conflict-free
        float g0 = sb[0 * 512 + t] + sb[1 * 512 + t] + sb[2 * 512 + t];
        float g1 = sb[0 * 512 + 256 + t] + sb[1 * 512 + 256 + t] + sb[2 * 512 + 256 + t];
        camWin(g0, hist + t);
        camWin(g1, hist + 256 + t);
        labelAccum(sb[3 * 512 + t], sb[4 * 512 + t],
                   sb[5 * 512 + t], sb[6 * 512 + t], pl0);
        labelAccum(sb[3 * 512 + 256 + t], sb[4 * 512 + 256 + t],
                   sb[5 * 512 + 256 + t], sb[6 * 512 + 256 + t], pl1);

        __builtin_amdgcn_sched_barrier(0);
        __builtin_amdgcn_s_barrier();       // protect stage[b%3] before re-stage
    }

    // read back batch-summed Pc (bins 0..15 at rows 2..17); own columns only
    float Pc0[KBINS], Pc1[KBINS];
    #pragma unroll
    for (int k = 0; k < KBINS; k++) {
        Pc0[k] = hist[(k + 2) * HCOLS + t];
        Pc1[k] = hist[(k + 2) * HCOLS + 256 + t];
    }

    // per-thread outer products
    float acc[NACC];
    #pragma unroll
    for (int k = 0; k < KBINS; k++) {
        #pragma unroll
        for (int c = 0; c < CBINS; c++)
            acc[k * 4 + c] = fmaf(Pc0[k], pl0[c], Pc1[k] * pl1[c]);
    }
    #pragma unroll
    for (int c = 0; c < CBINS; c++) acc[64 + c] = pl0[c] + pl1[c];

    // block reduction: butterfly (8-lane sums) -> LDS (reuse hist) -> 68 threads
    __syncthreads();
    float (*red)[NACC] = (float (*)[NACC])hist;
    const int lane = t & 63;
    const int wv   = t >> 6;

    #pragma unroll
    for (int i = 0; i < NACC; i++) {
        float v = acc[i];
        v += __shfl_xor(v, 1);
        v += __shfl_xor(v, 2);
        v += __shfl_xor(v, 4);
        if ((lane & 7) == 0) red[wv * 8 + (lane >> 3)][i] = v;
    }

    __syncthreads();
    if (t < NACC) {
        float s = 0.f;
        #pragma unroll
        for (int g = 0; g < 32; g++) s += red[g][t];
        ws[(size_t)blockIdx.x * NACC + t] = s;
    }
}

// Kernel 2: reduce 1024 block-partials in double, compute NID scalar.
__global__ void nid_final(const float* __restrict__ ws, float* __restrict__ out)
{
    __shared__ double partA[8][NACC];
    __shared__ double sm[NACC];
    __shared__ double tots[2];
    const int t = threadIdx.x;  // block of 544

    if (t < 8 * NACC) {
        int v = t % NACC;
        int g = t / NACC;
        double s = 0.0;
        #pragma unroll 8
        for (int i = g * 128; i < g * 128 + 128; i++)
            s += (double)ws[(size_t)i * NACC + v];
        partA[g][v] = s;
    }
    __syncthreads();
    if (t < NACC) {
        double s = 0.0;
        #pragma unroll
        for (int g = 0; g < 8; g++) s += partA[g][t];
        sm[t] = s;
    }
    __syncthreads();
    if (t == 0) {
        double a = 0, bb = 0;
        for (int v = 0; v < 64; v++) a += sm[v];
        for (int c = 0; c < 4; c++)  bb += sm[64 + c];
        tots[0] = a; tots[1] = bb;
    }
    __syncthreads();
    if (t < 64) {
        int k = t >> 2, c = t & 3;
        double pcl = sm[t] / tots[0];
        double pc  = (sm[k * 4] + sm[k * 4 + 1] + sm[k * 4 + 2] + sm[k * 4 + 3]) / tots[0];
        double pll = sm[64 + c] / tots[1];
        double lp  = log(pcl + 1e-7);
        double lo  = log(pc * pll + 1e-7);
        double dI  = pcl * (lp - lo);
        double dH  = -pcl * lp;
        #pragma unroll
        for (int mm = 1; mm < 64; mm <<= 1) {
            dI += __shfl_xor(dI, mm);
            dH += __shfl_xor(dH, mm);
        }
        if (t == 0) out[0] = (float)((1.0 - dI / dH - 0.95) * 20.0);
    }
}

extern "C" void kernel_launch(void* const* d_in, const int* in_sizes, int n_in,
                              void* d_out, int out_size, void* d_ws, size_t ws_size,
                              hipStream_t stream)
{
    const float* cam = (const float*)d_in[0];
    const float* lab = (const float*)d_in[1];
    float* ws = (float*)d_ws;

    hipLaunchKernelGGL(nid_partial, dim3(BLOCKS), dim3(TPB), 0, stream, cam, lab, ws);
    hipLaunchKernelGGL(nid_final, dim3(1), dim3(544), 0, stream, ws, (float*)d_out);
}